// Round 1
// baseline (316.140 us; speedup 1.0000x reference)
//
#include <hip/hip_runtime.h>
#include <math.h>

// Problem constants (match reference config)
#define GPB   8      // k-vectors (g) per reciprocal block
#define GTOT  729    // (2*NMAX+1)^3, NMAX=4

__global__ __launch_bounds__(256)
void ewald_fused(const float* __restrict__ pos,    // [T,3]
                 const float* __restrict__ chg,    // [T]
                 const float* __restrict__ cell,   // [Bn,3,3]
                 const int*   __restrict__ nm,     // [T,K]
                 const int*   __restrict__ shifts, // [T,K,3]
                 const int*   __restrict__ nnb,    // [T]
                 float* __restrict__ out,          // [Bn]
                 int T, int N, int K, int Bn,
                 int CB,   // number of reciprocal blocks (placed first)
                 int P)    // total pairs = T*K
{
    __shared__ float red[4][2 * GPB];

    const float TWO_PI  = 6.283185307179586f;
    const float ALPHA   = 0.3f;
    const float INV4A2  = 2.7777777777f;           // 1/(4*ALPHA^2)
    const float KC2     = 1.0f;                     // KCUT^2
    const float COUL    = 14.399645351950548f;
    const float INV_SQRT_PI = 0.5641895835477563f;

    int blk = blockIdx.x;

    if (blk < CB) {
        // ================= reciprocal space =================
        int gpb_groups = (GTOT + GPB - 1) / GPB;
        int b   = blk / gpb_groups;
        int grp = blk % gpb_groups;

        const float* C = cell + 9 * b;
        float m00=C[0], m01=C[1], m02=C[2];
        float m10=C[3], m11=C[4], m12=C[5];
        float m20=C[6], m21=C[7], m22=C[8];
        // adjugate (already laid out so inv[d][j] = a_dj/det)
        float a00 = m11*m22 - m12*m21;
        float a01 = m02*m21 - m01*m22;
        float a02 = m01*m12 - m02*m11;
        float a10 = m12*m20 - m10*m22;
        float a11 = m00*m22 - m02*m20;
        float a12 = m02*m10 - m00*m12;
        float a20 = m10*m21 - m11*m20;
        float a21 = m01*m20 - m00*m21;
        float a22 = m00*m11 - m01*m10;
        float det = m00*a00 + m01*a10 + m02*a20;
        float invdet = 1.0f / det;
        float vol = fabsf(det);

        float kvx[GPB], kvy[GPB], kvz[GPB], coef[GPB];
        #pragma unroll
        for (int gi = 0; gi < GPB; ++gi) {
            int g = grp * GPB + gi;
            float cf = 0.f, kx = 0.f, ky = 0.f, kz = 0.f;
            if (g < GTOT) {
                int ix = g / 81, rem = g - ix * 81;
                int iy = rem / 9, iz = rem - iy * 9;
                float nx = (float)(ix - 4), ny = (float)(iy - 4), nz = (float)(iz - 4);
                // kv_d = 2*pi * sum_j n_j * inv[d][j]
                kx = TWO_PI * invdet * (nx*a00 + ny*a01 + nz*a02);
                ky = TWO_PI * invdet * (nx*a10 + ny*a11 + nz*a12);
                kz = TWO_PI * invdet * (nx*a20 + ny*a21 + nz*a22);
                float k2 = kx*kx + ky*ky + kz*kz;
                if (k2 > 1e-10f && k2 <= KC2) {
                    cf = 12.566370614359172f * __expf(-k2 * INV4A2) / (k2 * 2.0f * vol);
                }
            }
            kvx[gi] = kx; kvy[gi] = ky; kvz[gi] = kz; coef[gi] = cf;
        }

        float Sre[GPB], Sim[GPB];
        #pragma unroll
        for (int gi = 0; gi < GPB; ++gi) { Sre[gi] = 0.f; Sim[gi] = 0.f; }

        const float* pb = pos + (size_t)3 * b * N;
        const float* qb = chg + (size_t)b * N;
        for (int a = threadIdx.x; a < N; a += 256) {
            float x = pb[3*a+0], y = pb[3*a+1], z = pb[3*a+2];
            float qa = qb[a];
            #pragma unroll
            for (int gi = 0; gi < GPB; ++gi) {
                if (coef[gi] != 0.f) {   // block-uniform -> s_cbranch_execz skip
                    float ph = x*kvx[gi] + y*kvy[gi] + z*kvz[gi];
                    float s, c;
                    __sincosf(ph, &s, &c);
                    Sre[gi] = fmaf(qa, c, Sre[gi]);
                    Sim[gi] = fmaf(qa, s, Sim[gi]);
                }
            }
        }

        // reduce: wave shuffle, then LDS across the 4 waves
        #pragma unroll
        for (int gi = 0; gi < GPB; ++gi) {
            #pragma unroll
            for (int off = 32; off > 0; off >>= 1) {
                Sre[gi] += __shfl_down(Sre[gi], off, 64);
                Sim[gi] += __shfl_down(Sim[gi], off, 64);
            }
        }
        int lane = threadIdx.x & 63;
        int w    = threadIdx.x >> 6;
        if (lane == 0) {
            #pragma unroll
            for (int gi = 0; gi < GPB; ++gi) {
                red[w][2*gi]   = Sre[gi];
                red[w][2*gi+1] = Sim[gi];
            }
        }
        __syncthreads();
        if (threadIdx.x < GPB) {
            int gi = threadIdx.x;
            float sr = red[0][2*gi]   + red[1][2*gi]   + red[2][2*gi]   + red[3][2*gi];
            float si = red[0][2*gi+1] + red[1][2*gi+1] + red[2][2*gi+1] + red[3][2*gi+1];
            float e = coef[gi] * (sr*sr + si*si);
            if (e != 0.f) atomicAdd(&out[b], COUL * e);
        }
    } else {
        // ================= real space =================
        int rb = blk - CB;
        int p  = rb * 256 + threadIdx.x;   // pair id
        float val = 0.0f;
        if (p < P) {
            int t = (int)((unsigned)p / (unsigned)K);
            int k = p - t * K;
            float qi = chg[t];
            if (k == 0) val = -ALPHA * INV_SQRT_PI * qi * qi;  // Gaussian self term
            int j = nm[p];
            bool msk = (j >= 0) && (k < nnb[t]);
            if (msk) {
                float xi = pos[3*t], yi = pos[3*t+1], zi = pos[3*t+2];
                int sx = shifts[3*p], sy = shifts[3*p+1], sz = shifts[3*p+2];
                float ox = 0.f, oy = 0.f, oz = 0.f;
                if ((sx | sy | sz) != 0) {          // rare path: periodic image shift
                    int b = t / N;
                    const float* C = cell + 9 * b;
                    float fx = (float)sx, fy = (float)sy, fz = (float)sz;
                    ox = fx*C[0] + fy*C[3] + fz*C[6];
                    oy = fx*C[1] + fy*C[4] + fz*C[7];
                    oz = fx*C[2] + fy*C[5] + fz*C[8];
                }
                float dx = pos[3*j+0] + ox - xi;
                float dy = pos[3*j+1] + oy - yi;
                float dz = pos[3*j+2] + oz - zi;
                float r2 = fmaf(dx, dx, fmaf(dy, dy, dz*dz));
                float rinv = rsqrtf(r2);
                float d = r2 * rinv;
                val += 0.5f * qi * chg[j] * erfcf(ALPHA * d) * rinv;
            }
        }
        // block reduce -> one atomic
        #pragma unroll
        for (int off = 32; off > 0; off >>= 1) val += __shfl_down(val, off, 64);
        int lane = threadIdx.x & 63;
        int w    = threadIdx.x >> 6;
        if (lane == 0) red[w][0] = val;
        __syncthreads();
        if (threadIdx.x == 0) {
            int t0 = (rb * 256) / K;      // block never straddles systems (N%4==0)
            int bs = t0 / N;
            atomicAdd(&out[bs],
                      COUL * (red[0][0] + red[1][0] + red[2][0] + red[3][0]));
        }
    }
}

extern "C" void kernel_launch(void* const* d_in, const int* in_sizes, int n_in,
                              void* d_out, int out_size, void* d_ws, size_t ws_size,
                              hipStream_t stream) {
    const float* pos    = (const float*)d_in[0];
    const float* chg    = (const float*)d_in[1];
    const float* cell   = (const float*)d_in[2];
    const int*   nm     = (const int*)d_in[3];
    const int*   shifts = (const int*)d_in[4];
    const int*   nnb    = (const int*)d_in[5];
    // d_in[6] (batch_idx) derivable as t/N — unused.

    int T  = in_sizes[1];          // 64000
    int Bn = in_sizes[2] / 9;      // 16
    int N  = T / Bn;               // 4000
    int K  = in_sizes[3] / T;      // 64
    int P  = T * K;                // 4,096,000 pairs
    int RB = (P + 255) / 256;      // real-space blocks
    int CB = Bn * ((GTOT + GPB - 1) / GPB);  // reciprocal blocks (first)

    // d_out is poisoned before every call — zero it (atomics accumulate into it)
    hipMemsetAsync(d_out, 0, (size_t)Bn * sizeof(float), stream);

    ewald_fused<<<CB + RB, 256, 0, stream>>>(pos, chg, cell, nm, shifts, nnb,
                                             (float*)d_out, T, N, K, Bn, CB, P);
}

// Round 2
// 124.890 us; speedup vs baseline: 2.5313x; 2.5313x over previous
//
#include <hip/hip_runtime.h>
#include <math.h>

// Problem constants (match reference config)
#define GPB    8      // k-vectors per reciprocal block
#define GTOT   729    // (2*NMAX+1)^3, NMAX=4
#define APB    16     // atoms per real-space block (256 thr = 4 waves x 4 atoms)
#define STRIDE 344    // partial slots per system: 250 real + 92 recip, padded

__device__ __forceinline__ float wave_reduce(float v) {
    #pragma unroll
    for (int off = 32; off > 0; off >>= 1) v += __shfl_down(v, off, 64);
    return v;
}

// -------- prologue: pack positions+charge into float4 for 1-line gathers ----
__global__ __launch_bounds__(256)
void pack_pq(const float* __restrict__ pos, const float* __restrict__ chg,
             float4* __restrict__ pq, int T)
{
    int t = blockIdx.x * 256 + threadIdx.x;
    if (t < T)
        pq[t] = make_float4(pos[3*t], pos[3*t+1], pos[3*t+2], chg[t]);
}

// -------- fused main kernel: recip blocks first, real-space behind ----------
template <bool PACKED>
__global__ __launch_bounds__(256)
void ewald_fused(const float4* __restrict__ pq,    // packed [T] (PACKED)
                 const float*  __restrict__ pos,   // [T,3]  (fallback)
                 const float*  __restrict__ chg,   // [T]    (fallback)
                 const float*  __restrict__ cell,  // [Bn,3,3]
                 const int*    __restrict__ nm,    // [T,K]
                 const int*    __restrict__ shifts,// [T,K,3]
                 const int*    __restrict__ nnb,   // [T]
                 float* __restrict__ partial,      // [Bn][STRIDE]
                 int T, int N, int K, int Bn, int CB)
{
    __shared__ float red[16];

    const float TWO_PI  = 6.283185307179586f;
    const float ALPHA   = 0.3f;
    const float INV4A2  = 2.7777777777f;            // 1/(4*ALPHA^2)
    const float KC2     = 1.0f;
    const float INV_SQRT_PI = 0.5641895835477563f;

    int blk = blockIdx.x;

    if (blk < CB) {
        // ======================= reciprocal space ==========================
        int gpb_groups = (GTOT + GPB - 1) / GPB;   // 92
        int b   = blk / gpb_groups;
        int grp = blk % gpb_groups;

        const float* C = cell + 9 * b;
        float m00=C[0], m01=C[1], m02=C[2];
        float m10=C[3], m11=C[4], m12=C[5];
        float m20=C[6], m21=C[7], m22=C[8];
        float a00 = m11*m22 - m12*m21;
        float a01 = m02*m21 - m01*m22;
        float a02 = m01*m12 - m02*m11;
        float a10 = m12*m20 - m10*m22;
        float a11 = m00*m22 - m02*m20;
        float a12 = m02*m10 - m00*m12;
        float a20 = m10*m21 - m11*m20;
        float a21 = m01*m20 - m00*m21;
        float a22 = m00*m11 - m01*m10;
        float det = m00*a00 + m01*a10 + m02*a20;
        float invdet = 1.0f / det;
        float vol = fabsf(det);

        float kvx[GPB], kvy[GPB], kvz[GPB], coef[GPB];
        bool any = false;
        #pragma unroll
        for (int gi = 0; gi < GPB; ++gi) {
            int g = grp * GPB + gi;
            float cf = 0.f, kx = 0.f, ky = 0.f, kz = 0.f;
            if (g < GTOT) {
                int ix = g / 81, rem = g - ix * 81;
                int iy = rem / 9, iz = rem - iy * 9;
                int nx = ix - 4, ny = iy - 4, nz = iz - 4;
                // half-sphere: keep lexicographically-positive n, double coef
                bool pos_half = (nx > 0) || (nx == 0 && (ny > 0 || (ny == 0 && nz > 0)));
                if (pos_half) {
                    float fx = (float)nx, fy = (float)ny, fz = (float)nz;
                    kx = TWO_PI * invdet * (fx*a00 + fy*a01 + fz*a02);
                    ky = TWO_PI * invdet * (fx*a10 + fy*a11 + fz*a12);
                    kz = TWO_PI * invdet * (fx*a20 + fy*a21 + fz*a22);
                    float k2 = kx*kx + ky*ky + kz*kz;
                    if (k2 > 1e-10f && k2 <= KC2) {
                        // 2 * [4*pi*exp(-k2/4a^2)/k2] / (2*vol)
                        cf = 12.566370614359172f * __expf(-k2 * INV4A2) / (k2 * vol);
                    }
                }
            }
            kvx[gi] = kx; kvy[gi] = ky; kvz[gi] = kz; coef[gi] = cf;
            any = any || (cf != 0.f);
        }

        int slot = b * STRIDE + (N / APB) + grp;   // recip slots after real slots
        if (!any) {                                // dead block: no atom loop
            if (threadIdx.x == 0) partial[slot] = 0.f;
            return;
        }

        float Sre[GPB], Sim[GPB];
        #pragma unroll
        for (int gi = 0; gi < GPB; ++gi) { Sre[gi] = 0.f; Sim[gi] = 0.f; }

        for (int a = threadIdx.x; a < N; a += 256) {
            float x, y, z, qa;
            if (PACKED) {
                float4 v = pq[(size_t)b * N + a];
                x = v.x; y = v.y; z = v.z; qa = v.w;
            } else {
                const float* pb = pos + (size_t)3 * (b * N + a);
                x = pb[0]; y = pb[1]; z = pb[2];
                qa = chg[(size_t)b * N + a];
            }
            #pragma unroll
            for (int gi = 0; gi < GPB; ++gi) {
                if (coef[gi] != 0.f) {             // block-uniform skip
                    float ph = x*kvx[gi] + y*kvy[gi] + z*kvz[gi];
                    float s, c;
                    __sincosf(ph, &s, &c);
                    Sre[gi] = fmaf(qa, c, Sre[gi]);
                    Sim[gi] = fmaf(qa, s, Sim[gi]);
                }
            }
        }

        // reduce each S over block, accumulate e over the 8 g's
        int lane = threadIdx.x & 63;
        int w    = threadIdx.x >> 6;
        float e_acc = 0.f;
        #pragma unroll
        for (int gi = 0; gi < GPB; ++gi) {
            if (coef[gi] != 0.f) {
                float sr = wave_reduce(Sre[gi]);
                float si = wave_reduce(Sim[gi]);
                if (lane == 0) { red[2*w] = sr; red[2*w+1] = si; }
                __syncthreads();
                if (threadIdx.x == 0) {
                    float SR = red[0] + red[2] + red[4] + red[6];
                    float SI = red[1] + red[3] + red[5] + red[7];
                    e_acc += coef[gi] * (SR*SR + SI*SI);
                }
                __syncthreads();
            }
        }
        if (threadIdx.x == 0) partial[slot] = e_acc;
    } else {
        // ========================== real space =============================
        int rb = blk - CB;
        int t0 = rb * APB;
        int sys = t0 / N;                 // APB divides N -> block in one system
        int lane = threadIdx.x & 63;
        int w    = threadIdx.x >> 6;

        float val = 0.0f;
        #pragma unroll
        for (int i = 0; i < APB/4; ++i) {
            int t = t0 + w * (APB/4) + i;
            float xi, yi, zi, qi;
            if (PACKED) {
                float4 v = pq[t];
                xi = v.x; yi = v.y; zi = v.z; qi = v.w;
            } else {
                xi = pos[3*t]; yi = pos[3*t+1]; zi = pos[3*t+2];
                qi = chg[t];
            }
            if (lane == 0) val -= ALPHA * INV_SQRT_PI * qi * qi; // self term
            int nn = nnb[t];
            for (int k = lane; k < K; k += 64) {
                int p = t * K + k;
                int j = nm[p];
                bool msk = (j >= 0) && (k < nn);
                if (msk) {
                    int sx = shifts[3*p], sy = shifts[3*p+1], sz = shifts[3*p+2];
                    float ox = 0.f, oy = 0.f, oz = 0.f;
                    if ((sx | sy | sz) != 0) {
                        const float* C = cell + 9 * sys;
                        float fx = (float)sx, fy = (float)sy, fz = (float)sz;
                        ox = fx*C[0] + fy*C[3] + fz*C[6];
                        oy = fx*C[1] + fy*C[4] + fz*C[7];
                        oz = fx*C[2] + fy*C[5] + fz*C[8];
                    }
                    float xj, yj, zj, qj;
                    if (PACKED) {
                        float4 v = pq[j];
                        xj = v.x; yj = v.y; zj = v.z; qj = v.w;
                    } else {
                        xj = pos[3*j]; yj = pos[3*j+1]; zj = pos[3*j+2];
                        qj = chg[j];
                    }
                    float dx = xj + ox - xi;
                    float dy = yj + oy - yi;
                    float dz = zj + oz - zi;
                    float r2 = fmaf(dx, dx, fmaf(dy, dy, dz*dz));
                    float rinv = rsqrtf(r2);
                    float d = r2 * rinv;
                    val += 0.5f * qi * qj * erfcf(ALPHA * d) * rinv;
                }
            }
        }

        val = wave_reduce(val);
        if (lane == 0) red[w] = val;
        __syncthreads();
        if (threadIdx.x == 0) {
            int rb_in_sys = rb - sys * (N / APB);
            partial[sys * STRIDE + rb_in_sys] =
                red[0] + red[1] + red[2] + red[3];
        }
    }
}

// -------- epilogue: per-system sum of partials, apply Coulomb constant -----
__global__ __launch_bounds__(256)
void final_reduce(const float* __restrict__ partial, float* __restrict__ out,
                  int nslots)
{
    __shared__ float red[4];
    const float COUL = 14.399645351950548f;
    int b = blockIdx.x;
    float v = 0.f;
    for (int s = threadIdx.x; s < nslots; s += 256)
        v += partial[b * STRIDE + s];
    v = wave_reduce(v);
    int lane = threadIdx.x & 63, w = threadIdx.x >> 6;
    if (lane == 0) red[w] = v;
    __syncthreads();
    if (threadIdx.x == 0)
        out[b] = COUL * (red[0] + red[1] + red[2] + red[3]);
}

extern "C" void kernel_launch(void* const* d_in, const int* in_sizes, int n_in,
                              void* d_out, int out_size, void* d_ws, size_t ws_size,
                              hipStream_t stream) {
    const float* pos    = (const float*)d_in[0];
    const float* chg    = (const float*)d_in[1];
    const float* cell   = (const float*)d_in[2];
    const int*   nm     = (const int*)d_in[3];
    const int*   shifts = (const int*)d_in[4];
    const int*   nnb    = (const int*)d_in[5];

    int T  = in_sizes[1];          // 64000
    int Bn = in_sizes[2] / 9;      // 16
    int N  = T / Bn;               // 4000
    int K  = in_sizes[3] / T;      // 64
    int CB = Bn * ((GTOT + GPB - 1) / GPB);   // 1472 recip blocks
    int RB = T / APB;                          // 4000 real blocks
    int nslots = (N / APB) + ((GTOT + GPB - 1) / GPB);  // 342

    size_t partBytes = (size_t)Bn * STRIDE * sizeof(float);
    size_t packOff   = ((partBytes + 255) / 256) * 256;
    size_t packBytes = (size_t)T * sizeof(float4);

    float*  partial = (float*)d_ws;
    bool packed = (ws_size >= packOff + packBytes);

    if (packed) {
        float4* pq = (float4*)((char*)d_ws + packOff);
        pack_pq<<<(T + 255) / 256, 256, 0, stream>>>(pos, chg, pq, T);
        ewald_fused<true><<<CB + RB, 256, 0, stream>>>(
            pq, pos, chg, cell, nm, shifts, nnb, partial, T, N, K, Bn, CB);
    } else {
        ewald_fused<false><<<CB + RB, 256, 0, stream>>>(
            nullptr, pos, chg, cell, nm, shifts, nnb, partial, T, N, K, Bn, CB);
    }
    final_reduce<<<Bn, 256, 0, stream>>>(partial, (float*)d_out, nslots);
}